// Round 1
// baseline (70.081 us; speedup 1.0000x reference)
//
#include <hip/hip_runtime.h>
#include <stdint.h>

#define NQ 900
#define TOPK_PRE 100
#define TOPK_POST 20
#define IOU_THR 0.7f
#define SORT_N 1024
#define THREADS 256

// Output layout (float32):
//   sel_s : [0,      20480)   (16,64,20)
//   sel_b : [20480, 102400)   (16,64,20,4)
//   sel_l : [102400,122880)   (16,64,20)  (float-encoded ints, -1 invalid)
//   vmask : [122880,143360)   (16,64,20)  (0.0 / 1.0)

__global__ __launch_bounds__(THREADS)
void ovnms_kernel(const float* __restrict__ logits,   // (16,1,57600,2)
                  const float* __restrict__ boxes,    // (16,1,57600,4)
                  const float* __restrict__ tsize,    // (16,2) [h,w]
                  const int*   __restrict__ labels,   // (16,64)
                  float* __restrict__ out)
{
#pragma clang fp contract(off)
    const int row = blockIdx.x;        // b*64 + p
    const int b   = row >> 6;
    const int p   = row & 63;
    const int tid = threadIdx.x;

    __shared__ unsigned long long sk[SORT_N];
    __shared__ float x1s[TOPK_PRE], y1s[TOPK_PRE], x2s[TOPK_PRE], y2s[TOPK_PRE];
    __shared__ float areas[TOPK_PRE], scs[TOPK_PRE];
    __shared__ int   keep[TOPK_PRE];
    __shared__ int   slots[TOPK_POST];
    __shared__ int   nkeep;

    // ---- 1. sigmoid scores -> sort keys (descending score, ascending index) ----
    const float* lrow = logits + ((size_t)b * 57600 + (size_t)p * NQ) * 2;
    for (int q = tid; q < SORT_N; q += THREADS) {
        unsigned long long key;
        if (q < NQ) {
            float x = lrow[q * 2 + 1];           // channel -1 == 1
            float s = 1.0f / (1.0f + expf(-x));  // sigmoid, f32; s in (0,1)
            unsigned u = __float_as_uint(s);     // positive floats: bit order == value order
            key = ((unsigned long long)(~u) << 32) | (unsigned)q;
        } else {
            key = 0xFFFFFFFFFFFFFFFFull;         // pad sorts last
        }
        sk[q] = key;
    }

    // ---- 2. bitonic sort 1024 keys ascending (=> best score first) ----
    for (int k = 2; k <= SORT_N; k <<= 1) {
        for (int j = k >> 1; j > 0; j >>= 1) {
            __syncthreads();
            for (int i = tid; i < SORT_N; i += THREADS) {
                int ixj = i ^ j;
                if (ixj > i) {
                    unsigned long long a = sk[i];
                    unsigned long long c = sk[ixj];
                    bool up = ((i & k) == 0);
                    if ((a > c) == up) { sk[i] = c; sk[ixj] = a; }
                }
            }
        }
    }
    __syncthreads();

    // ---- 3. gather top-100 boxes, scale to xyxy, areas ----
    if (tid < TOPK_PRE) {
        unsigned long long key = sk[tid];
        int q = (int)(key & 0xFFFFFFFFu);
        float s = __uint_as_float(~(unsigned)(key >> 32));
        scs[tid] = s;

        const float* brow = boxes + ((size_t)b * 57600 + (size_t)p * NQ + (size_t)q) * 4;
        float cx = brow[0], cy = brow[1], w = brow[2], h = brow[3];
        float ih = tsize[b * 2 + 0];
        float iw = tsize[b * 2 + 1];
        // exact numpy op order: (cx - 0.5*w) then * scale  (contract off)
        float xa = (cx - 0.5f * w) * iw;
        float ya = (cy - 0.5f * h) * ih;
        float xb = (cx + 0.5f * w) * iw;
        float yb = (cy + 0.5f * h) * ih;
        x1s[tid] = xa; y1s[tid] = ya; x2s[tid] = xb; y2s[tid] = yb;
        areas[tid] = fmaxf(xb - xa, 0.0f) * fmaxf(yb - ya, 0.0f);
        keep[tid] = 1;
    }
    __syncthreads();

    // ---- 4. greedy NMS (exact reference semantics) ----
    for (int i = 0; i < TOPK_PRE; ++i) {
        __syncthreads();
        if (!keep[i]) continue;          // uniform branch (LDS broadcast)
        int t = tid;
        if (t > i && t < TOPK_PRE && keep[t]) {
            float ltx = fmaxf(x1s[i], x1s[t]);
            float lty = fmaxf(y1s[i], y1s[t]);
            float rbx = fminf(x2s[i], x2s[t]);
            float rby = fminf(y2s[i], y2s[t]);
            float wx = fmaxf(rbx - ltx, 0.0f);
            float wy = fmaxf(rby - lty, 0.0f);
            float inter = wx * wy;
            float iou = inter / (((areas[i] + areas[t]) - inter) + 1e-7f);
            if (iou > IOU_THR) keep[t] = 0;
        }
    }
    __syncthreads();

    // ---- 5. rank survivors, take first 20 ----
    if (tid == 0) {
        int r = 0;
        for (int i = 0; i < TOPK_PRE && r < TOPK_POST; ++i)
            if (keep[i]) slots[r++] = i;
        nkeep = r;
    }
    __syncthreads();

    // ---- 6. write outputs ----
    if (tid < TOPK_POST) {
        size_t o = (size_t)row * TOPK_POST + (size_t)tid;
        float s = 0.0f, xa = 0.0f, ya = 0.0f, xb = 0.0f, yb = 0.0f;
        float lab = -1.0f, m = 0.0f;
        if (tid < nkeep) {
            int i = slots[tid];
            s = scs[i];
            xa = x1s[i]; ya = y1s[i]; xb = x2s[i]; yb = y2s[i];
            lab = (float)labels[row];
            m = 1.0f;
        }
        out[o] = s;
        float* ob = out + 20480 + o * 4;
        ob[0] = xa; ob[1] = ya; ob[2] = xb; ob[3] = yb;
        out[102400 + o] = lab;
        out[122880 + o] = m;
    }
}

extern "C" void kernel_launch(void* const* d_in, const int* in_sizes, int n_in,
                              void* d_out, int out_size, void* d_ws, size_t ws_size,
                              hipStream_t stream) {
    const float* logits = (const float*)d_in[0];
    const float* boxes  = (const float*)d_in[1];
    const float* tsize  = (const float*)d_in[2];
    const int*   labels = (const int*)d_in[3];
    float* out = (float*)d_out;

    ovnms_kernel<<<dim3(1024), dim3(THREADS), 0, stream>>>(logits, boxes, tsize, labels, out);
}

// Round 2
// 38.266 us; speedup vs baseline: 1.8314x; 1.8314x over previous
//
#include <hip/hip_runtime.h>
#include <stdint.h>

#define NQ 900
#define TOPK_PRE 100
#define TOPK_POST 20
#define IOU_THR 0.7f
#define THREADS 256

typedef unsigned long long u64;

// Output layout (float32):
//   sel_s : [0,      20480)   (16,64,20)
//   sel_b : [20480, 102400)   (16,64,20,4)
//   sel_l : [102400,122880)   (16,64,20)
//   vmask : [122880,143360)   (16,64,20)

__global__ __launch_bounds__(THREADS)
void ovnms_kernel(const float* __restrict__ logits,   // (16,1,57600,2)
                  const float* __restrict__ boxes,    // (16,1,57600,4)
                  const float* __restrict__ tsize,    // (16,2) [h,w]
                  const int*   __restrict__ labels,   // (16,64)
                  float* __restrict__ out)
{
#pragma clang fp contract(off)
    const int row = blockIdx.x;        // b*64 + p
    const int b   = row >> 6;
    const int p   = row & 63;
    const int tid = threadIdx.x;
    const int lane = tid & 63;
    const int wid  = tid >> 6;

    __shared__ int hist[256];
    __shared__ u64 sel[128];
    __shared__ u64 sortk[128];
    __shared__ u64 sup0[TOPK_PRE], sup1[TOPK_PRE];
    __shared__ float x1s[TOPK_PRE], y1s[TOPK_PRE], x2s[TOPK_PRE], y2s[TOPK_PRE];
    __shared__ float areas[TOPK_PRE], scs[TOPK_PRE];
    __shared__ int   slots[TOPK_POST];
    __shared__ int   nkeep, sh_cnt, sh_rn, sh_done;
    __shared__ u64   sh_prefix, sh_pivot;

    // ---- 1. sigmoid scores -> 4 keys per thread (registers) ----
    const float* lrow = logits + ((size_t)b * 57600 + (size_t)p * NQ) * 2;
    u64 kreg[4];
#pragma unroll
    for (int t = 0; t < 4; ++t) {
        int q = tid + t * THREADS;
        u64 key = ~0ull;
        if (q < NQ) {
            float x = lrow[q * 2 + 1];
            float s = 1.0f / (1.0f + expf(-x));
            unsigned u = __float_as_uint(s);
            key = ((u64)(~u) << 32) | (unsigned)q;
        }
        kreg[t] = key;
    }

    if (tid == 0) { sh_prefix = 0; sh_rn = TOPK_PRE; sh_done = 0; sh_pivot = ~0ull; }

    // ---- 2. radix-select the exact 100th-smallest key (keys distinct) ----
    for (int d = 7; d >= 0; --d) {
        __syncthreads();
        if (sh_done) break;
        hist[tid] = 0;
        __syncthreads();
        const int sh1 = 8 * d + 8;
        const u64 pref = sh_prefix;
        const int rn = sh_rn;
#pragma unroll
        for (int t = 0; t < 4; ++t) {
            u64 k = kreg[t];
            bool match = (sh1 >= 64) || ((k >> sh1) == pref);
            if (match) atomicAdd(&hist[(int)((k >> (8 * d)) & 0xFF)], 1);
        }
        __syncthreads();
        if (tid < 64) {
            int c0 = hist[tid * 4 + 0], c1 = hist[tid * 4 + 1];
            int c2 = hist[tid * 4 + 2], c3 = hist[tid * 4 + 3];
            int s = c0 + c1 + c2 + c3;
            int inc = s;
            for (int off = 1; off < 64; off <<= 1) {
                int v = __shfl_up(inc, off);
                if (tid >= off) inc += v;
            }
            int exc = inc - s;
            bool mine = (rn > exc) && (rn <= inc);
            int B = 0, cumB = 0, cntB = 0;
            if (mine) {
                int cum = exc;
                int cc[4] = {c0, c1, c2, c3};
#pragma unroll
                for (int t = 0; t < 4; ++t) {
                    if (rn > cum && rn <= cum + cc[t]) { B = tid * 4 + t; cumB = cum; cntB = cc[t]; }
                    cum += cc[t];
                }
            }
            u64 bal = __ballot(mine);
            int src = __ffsll((unsigned long long)bal) - 1;
            B    = __shfl(B, src);
            cumB = __shfl(cumB, src);
            cntB = __shfl(cntB, src);
            if (tid == 0) {
                int nrn = rn - cumB;
                u64 npref = (pref << 8) | (unsigned)B;
                sh_prefix = npref;
                sh_rn = nrn;
                if (nrn == cntB) {
                    sh_done = 1;
                    sh_pivot = ((npref + 1) << (8 * d)) - 1;
                }
            }
        }
    }

    // ---- 3. compact winners (key <= pivot) into LDS ----
    if (tid < 128) sel[tid] = ~0ull;
    if (tid == 0) sh_cnt = 0;
    __syncthreads();
    const u64 P = sh_pivot;
#pragma unroll
    for (int t = 0; t < 4; ++t) {
        u64 k = kreg[t];
        if (k <= P) { int pos = atomicAdd(&sh_cnt, 1); sel[pos] = k; }
    }
    __syncthreads();

    // ---- 4. wave-0 bitonic sort of 128 keys (no barriers) ----
    if (tid < 64) {
        u64 va = sel[tid], vb = sel[tid + 64];
        for (int k = 2; k <= 128; k <<= 1) {
            for (int j = k >> 1; j; j >>= 1) {
                if (j == 64) {
                    bool up = ((tid & k) == 0);
                    u64 lo = va < vb ? va : vb;
                    u64 hi = va < vb ? vb : va;
                    va = up ? lo : hi;
                    vb = up ? hi : lo;
                } else {
                    u64 pa = __shfl_xor(va, j);
                    u64 pb = __shfl_xor(vb, j);
                    bool lower = ((tid & j) == 0);
                    bool dirA = ((tid & k) == 0);
                    bool dirB = (((tid + 64) & k) == 0);
                    va = (dirA == lower) ? (va < pa ? va : pa) : (va > pa ? va : pa);
                    vb = (dirB == lower) ? (vb < pb ? vb : pb) : (vb > pb ? vb : pb);
                }
            }
        }
        sortk[tid] = va;
        sortk[tid + 64] = vb;
    }
    __syncthreads();

    // ---- 5. gather top-100 boxes, scale, areas ----
    if (tid < TOPK_PRE) {
        u64 key = sortk[tid];
        int q = (int)(key & 0xFFFFFFFFu);
        scs[tid] = __uint_as_float(~(unsigned)(key >> 32));
        const float* brow = boxes + ((size_t)b * 57600 + (size_t)p * NQ + (size_t)q) * 4;
        float cx = brow[0], cy = brow[1], w = brow[2], h = brow[3];
        float ih = tsize[b * 2 + 0];
        float iw = tsize[b * 2 + 1];
        float xa = (cx - 0.5f * w) * iw;
        float ya = (cy - 0.5f * h) * ih;
        float xb = (cx + 0.5f * w) * iw;
        float yb = (cy + 0.5f * h) * ih;
        x1s[tid] = xa; y1s[tid] = ya; x2s[tid] = xb; y2s[tid] = yb;
        areas[tid] = fmaxf(xb - xa, 0.0f) * fmaxf(yb - ya, 0.0f);
    }
    __syncthreads();

    // ---- 6. suppression bit-matrix via ballot (no barriers inside) ----
    for (int i = wid; i < TOPK_PRE; i += 4) {
        float xi1 = x1s[i], yi1 = y1s[i], xi2 = x2s[i], yi2 = y2s[i], ai = areas[i];
        int j = lane;
        bool b0 = false;
        if (j < i) {
            float ltx = fmaxf(xi1, x1s[j]);
            float lty = fmaxf(yi1, y1s[j]);
            float rbx = fminf(xi2, x2s[j]);
            float rby = fminf(yi2, y2s[j]);
            float wx = fmaxf(rbx - ltx, 0.0f);
            float wy = fmaxf(rby - lty, 0.0f);
            float inter = wx * wy;
            float iou = inter / (((ai + areas[j]) - inter) + 1e-7f);
            b0 = iou > IOU_THR;
        }
        u64 m0 = __ballot(b0);
        j = 64 + lane;
        bool b1 = false;
        if (j < i) {
            float ltx = fmaxf(xi1, x1s[j]);
            float lty = fmaxf(yi1, y1s[j]);
            float rbx = fminf(xi2, x2s[j]);
            float rby = fminf(yi2, y2s[j]);
            float wx = fmaxf(rbx - ltx, 0.0f);
            float wy = fmaxf(rby - lty, 0.0f);
            float inter = wx * wy;
            float iou = inter / (((ai + areas[j]) - inter) + 1e-7f);
            b1 = iou > IOU_THR;
        }
        u64 m1 = __ballot(b1);
        if (lane == 0) { sup0[i] = m0; sup1[i] = m1; }
    }
    __syncthreads();

    // ---- 7. greedy scan over bitmasks (single thread, pure ALU) ----
    if (tid == 0) {
        u64 kept0 = 0, kept1 = 0;
        int r = 0;
#pragma unroll 10
        for (int i = 0; i < TOPK_PRE; ++i) {
            u64 s0 = sup0[i] & kept0;
            u64 s1 = sup1[i] & kept1;
            if ((s0 | s1) == 0ull) {
                if (i < 64) kept0 |= 1ull << i;
                else        kept1 |= 1ull << (i - 64);
                if (r < TOPK_POST) slots[r] = i;
                r++;
            }
        }
        nkeep = r < TOPK_POST ? r : TOPK_POST;
    }
    __syncthreads();

    // ---- 8. write outputs ----
    if (tid < TOPK_POST) {
        size_t o = (size_t)row * TOPK_POST + (size_t)tid;
        float s = 0.0f, xa = 0.0f, ya = 0.0f, xb = 0.0f, yb = 0.0f;
        float lab = -1.0f, m = 0.0f;
        if (tid < nkeep) {
            int i = slots[tid];
            s = scs[i];
            xa = x1s[i]; ya = y1s[i]; xb = x2s[i]; yb = y2s[i];
            lab = (float)labels[row];
            m = 1.0f;
        }
        out[o] = s;
        float* ob = out + 20480 + o * 4;
        ob[0] = xa; ob[1] = ya; ob[2] = xb; ob[3] = yb;
        out[102400 + o] = lab;
        out[122880 + o] = m;
    }
}

extern "C" void kernel_launch(void* const* d_in, const int* in_sizes, int n_in,
                              void* d_out, int out_size, void* d_ws, size_t ws_size,
                              hipStream_t stream) {
    const float* logits = (const float*)d_in[0];
    const float* boxes  = (const float*)d_in[1];
    const float* tsize  = (const float*)d_in[2];
    const int*   labels = (const int*)d_in[3];
    float* out = (float*)d_out;

    ovnms_kernel<<<dim3(1024), dim3(THREADS), 0, stream>>>(logits, boxes, tsize, labels, out);
}